// Round 10
// baseline (136.174 us; speedup 1.0000x reference)
//
#include <hip/hip_runtime.h>

#define NLEV 127.0f
#define QEPS 1e-8f
#define SCAN_BLOCKS 2048
#define NLEAF 64

// ws float layout:
// [0]           root counter (uint)   — zeroed by hipMemsetAsync each call
// [1..64]       leaf counters (uint)  — zeroed by hipMemsetAsync each call
// [128..2175]   per-scan-block |x| partial maxima
// [2304..2383]  T_lin[5][16]  (s-independent composite linear map)
// [2432..2564]  bpre[133] = b/w_sf, [l0:64 | l1:32 | l2:32 | l3:5]
// [2576..3240]  C[5][133] row-major bias-coefficient matrix (incl. L3 diag)
// [3328]        inv_s
// [3329..3408]  M[5][16] (pre-scaled by s)
// [3409..3413]  c[5]
#define WS_ROOT 0
#define WS_LEAF 1
#define WS_PART 128
#define WS_TLIN 2304
#define WS_BPRE 2432
#define WS_C    2576
#define WS_FIN  3328

__device__ __forceinline__ float max4(float4 v) {
    return fmaxf(fmaxf(fabsf(v.x), fabsf(v.y)), fmaxf(fabsf(v.z), fabsf(v.w)));
}
__device__ __forceinline__ float clipr(float v) {
    return fminf(fmaxf(rintf(v), -NLEV), NLEV);
}
__device__ __forceinline__ float aload(const float* p) {
    return __hip_atomic_load(p, __ATOMIC_RELAXED, __HIP_MEMORY_SCOPE_AGENT);
}

// ---- k1: block 0 composes s-independent weight math (dispatched FIRST so it
//      overlaps the scan); blocks 1..SCAN_BLOCKS scan |x| -> partials.
//      Last-arriver (two-level counter tree — single-address atomics serialize
//      ~20ns each, R8 lesson) runs the s-dependent finalize inline. ----
__global__ void __launch_bounds__(256) k1_all(
        const float4* __restrict__ x4,
        const float* __restrict__ w0, const float* __restrict__ b0,
        const float* __restrict__ w2, const float* __restrict__ b2,
        const float* __restrict__ w4, const float* __restrict__ b4,
        const float* __restrict__ w6, const float* __restrict__ b6,
        float* __restrict__ ws, int n4) {
    const int t = threadIdx.x;
    __shared__ float sm[4];
    __shared__ int isLast;
    __shared__ float bi[133];
    __shared__ float s_sh;
    // compose-branch LDS (also reused by nothing else; ~12.5 KB total)
    __shared__ float Wq[2048];
    __shared__ float Rm[320], Rn[320], Cm[320];
    __shared__ float sfv[64];
    __shared__ unsigned rmax[64];

    if (blockIdx.x == 0) {
        // ---- compose (entirely s-independent), layers processed 3 -> 0 ----
        const float* Wl[4] = {w0, w2, w4, w6};
        const float* Bl[4] = {b0, b2, b4, b6};
        const int Ol[4] = {64, 32, 32, 5};
        const int Fl[4] = {16, 64, 32, 32};
        const int bpre_off[4] = {0, 64, 96, 128};
        const int cs_base[4]  = {0, 64, 96, 128};

        for (int L = 3; L >= 0; --L) {
            const int O = Ol[L], F = Fl[L];
            const float* W = Wl[L];
            const float* Bb = Bl[L];
            if (t < 64) rmax[t] = 0u;
            __syncthreads();
            const int nf4 = O * F / 4, f4row = F / 4;
            for (int i = t; i < nf4; i += 256) {
                float4 wv = ((const float4*)W)[i];
                atomicMax(&rmax[i / f4row], __float_as_uint(max4(wv)));
            }
            __syncthreads();
            if (t < O) {
                float sf = fmaxf(__uint_as_float(rmax[t]) / NLEV, QEPS);
                sfv[t] = sf;
                ws[WS_BPRE + bpre_off[L] + t] = Bb[t] / sf;
            }
            __syncthreads();
            for (int i = t; i < O * F; i += 256)
                Wq[i] = clipr(W[i] / sfv[i / F]);
            __syncthreads();

            if (L == 3) {
                for (int i = t; i < 5 * F; i += 256) Rm[i] = sfv[i / F] * Wq[i];
                if (t < 25) {
                    int oo = t / 5, k = t % 5;
                    ws[WS_C + oo * 133 + cs_base[3] + k] = (k == oo) ? sfv[oo] : 0.f;
                }
                __syncthreads();
            } else {
                for (int i = t; i < 5 * O; i += 256) {
                    int r = i / O, c0 = i % O;
                    float v = Rm[r * O + c0] * sfv[c0];
                    Cm[i] = v;
                    ws[WS_C + r * 133 + cs_base[L] + c0] = v;
                }
                __syncthreads();
                for (int i = t; i < 5 * F; i += 256) {
                    int r = i / F, c0 = i % F;
                    float acc = 0.f;
                    #pragma unroll 8
                    for (int j = 0; j < O; ++j) acc += Cm[r * O + j] * Wq[j * F + c0];
                    Rn[i] = acc;
                }
                __syncthreads();
                if (L == 0) {
                    for (int i = t; i < 80; i += 256) ws[WS_TLIN + i] = Rn[i];
                } else {
                    for (int i = t; i < 5 * F; i += 256) Rm[i] = Rn[i];
                    __syncthreads();
                }
            }
        }
    } else {
        // ---- scan chunk (blockIdx.x - 1) ----
        const int cid = blockIdx.x - 1;
        const int tid = cid * 256 + t;
        const int stride = SCAN_BLOCKS * 256;
        float m[8];
        #pragma unroll
        for (int k = 0; k < 8; ++k) m[k] = 0.f;
        int i = tid;
        for (; i + 7 * stride < n4; i += 8 * stride) {
            #pragma unroll
            for (int k = 0; k < 8; ++k) m[k] = fmaxf(m[k], max4(x4[i + k * stride]));
        }
        for (; i < n4; i += stride) m[0] = fmaxf(m[0], max4(x4[i]));
        float mm = fmaxf(fmaxf(fmaxf(m[0], m[1]), fmaxf(m[2], m[3])),
                         fmaxf(fmaxf(m[4], m[5]), fmaxf(m[6], m[7])));
        #pragma unroll
        for (int off = 32; off > 0; off >>= 1)
            mm = fmaxf(mm, __shfl_down(mm, off, 64));
        if ((t & 63) == 0) sm[t >> 6] = mm;
        __syncthreads();
        if (t == 0)
            ws[WS_PART + cid] = fmaxf(fmaxf(sm[0], sm[1]), fmaxf(sm[2], sm[3]));
    }

    // ---- arrival: two-level counter tree; last arriver finalizes ----
    __syncthreads();            // all block writes issued
    if (t == 0) {
        __threadfence();        // write back this XCD's L2 (release)
        unsigned* leaf = (unsigned*)ws + WS_LEAF;
        unsigned* root = (unsigned*)ws + WS_ROOT;
        const int li = blockIdx.x & (NLEAF - 1);
        const unsigned expected = 32u + (li == 0 ? 1u : 0u);  // 2049 blocks total
        int last = 0;
        unsigned prev = __hip_atomic_fetch_add(&leaf[li], 1u,
                            __ATOMIC_ACQ_REL, __HIP_MEMORY_SCOPE_AGENT);
        if (prev == expected - 1u) {
            unsigned rprev = __hip_atomic_fetch_add(root, 1u,
                                __ATOMIC_ACQ_REL, __HIP_MEMORY_SCOPE_AGENT);
            if (rprev == NLEAF - 1u) last = 1;
        }
        isLast = last;
    }
    __syncthreads();
    if (!isLast) return;

    // ---- finalize (runs in exactly one block; agent-scope loads for coherence) ----
    float pm = 0.f;
    for (int i = t; i < SCAN_BLOCKS; i += 256)
        pm = fmaxf(pm, aload(&ws[WS_PART + i]));
    #pragma unroll
    for (int off = 32; off > 0; off >>= 1)
        pm = fmaxf(pm, __shfl_down(pm, off, 64));
    if ((t & 63) == 0) sm[t >> 6] = pm;
    __syncthreads();
    if (t == 0) {
        float am = fmaxf(fmaxf(sm[0], sm[1]), fmaxf(sm[2], sm[3]));
        s_sh = fmaxf(am / NLEV, QEPS);
    }
    __syncthreads();
    const float s = s_sh;
    const float inv_s = 1.0f / s;

    if (t < 133) bi[t] = clipr(aload(&ws[WS_BPRE + t]) * inv_s);
    __syncthreads();
    if (t < 160) {
        // c[oo] = s * dot(C[oo][:], bi) — groups ALIGNED to 32-lane boundaries
        // (R8 bug: an 80-lane offset made shfl groups straddle inactive lanes)
        const int oo = t >> 5, lane = t & 31;
        float acc = 0.f;
        for (int j = lane; j < 133; j += 32)
            acc += aload(&ws[WS_C + oo * 133 + j]) * bi[j];
        #pragma unroll
        for (int off = 16; off > 0; off >>= 1)
            acc += __shfl_xor(acc, off, 32);
        if (lane == 0) ws[WS_FIN + 81 + oo] = acc * s;
    } else if (t < 240) {
        ws[WS_FIN + 1 + (t - 160)] = aload(&ws[WS_TLIN + (t - 160)]) * s;
    } else if (t == 240) {
        ws[WS_FIN] = inv_s;
    }
}

// ---- k2: minimal-prologue streaming main pass (R8/R9 version, ~10us) ----
__global__ void __launch_bounds__(256, 6) k2_main(const float4* __restrict__ x4,
                                                  const float* __restrict__ ws,
                                                  float4* __restrict__ out4,
                                                  int nTiles) {
    __shared__ __align__(16) float ostage[640];
    const int t = threadIdx.x;
    const int v = t & 3;
    const int lrow = t >> 2;

    const float inv_s = ws[WS_FIN];
    float Mreg[5][4], cadd[5];
    #pragma unroll
    for (int oo = 0; oo < 5; ++oo) {
        cadd[oo] = ws[WS_FIN + 81 + oo];
        #pragma unroll
        for (int j = 0; j < 4; ++j)
            Mreg[oo][j] = ws[WS_FIN + 1 + oo * 16 + v * 4 + j];
    }

    int parity = 0;
    int tile = blockIdx.x;
    float4 xv = make_float4(0.f, 0.f, 0.f, 0.f);
    if (tile < nTiles) xv = x4[(size_t)tile * 256 + t];
    for (; tile < nTiles; tile += gridDim.x, parity ^= 1) {
        const int nt = tile + gridDim.x;
        float4 xn = make_float4(0.f, 0.f, 0.f, 0.f);
        if (nt < nTiles) xn = x4[(size_t)nt * 256 + t];

        float q0 = fminf(fmaxf(rintf(xv.x * inv_s), -NLEV), NLEV);
        float q1 = fminf(fmaxf(rintf(xv.y * inv_s), -NLEV), NLEV);
        float q2 = fminf(fmaxf(rintf(xv.z * inv_s), -NLEV), NLEV);
        float q3 = fminf(fmaxf(rintf(xv.w * inv_s), -NLEV), NLEV);

        float* buf = ostage + (parity ? 320 : 0);
        float p[5];
        #pragma unroll
        for (int oo = 0; oo < 5; ++oo) {
            float acc = fmaf(q0, Mreg[oo][0],
                        fmaf(q1, Mreg[oo][1],
                        fmaf(q2, Mreg[oo][2], q3 * Mreg[oo][3])));
            acc += __shfl_xor(acc, 1, 64);
            acc += __shfl_xor(acc, 2, 64);
            p[oo] = acc;
        }
        if (v == 0) {
            #pragma unroll
            for (int oo = 0; oo < 5; ++oo) buf[lrow * 5 + oo] = p[oo] + cadd[oo];
        }
        __syncthreads();
        if (t < 80) out4[(size_t)tile * 80 + t] = ((const float4*)buf)[t];
        xv = xn;
    }
}

// ---- tail rows (only launched when B % 64 != 0) ----
__global__ void __launch_bounds__(256) k_tail(const float* __restrict__ x,
                                              const float* __restrict__ ws,
                                              float* __restrict__ out,
                                              int tailStart, int B) {
    const int r = tailStart + blockIdx.x * 256 + threadIdx.x;
    if (r >= B) return;
    const float inv_s = ws[WS_FIN];
    const float* xr = x + (size_t)r * 16;
    float q[16];
    #pragma unroll
    for (int i = 0; i < 16; ++i)
        q[i] = fminf(fmaxf(rintf(xr[i] * inv_s), -NLEV), NLEV);
    #pragma unroll
    for (int oo = 0; oo < 5; ++oo) {
        float acc = ws[WS_FIN + 81 + oo];
        #pragma unroll
        for (int i = 0; i < 16; ++i) acc = fmaf(q[i], ws[WS_FIN + 1 + oo * 16 + i], acc);
        out[(size_t)r * 5 + oo] = acc;
    }
}

extern "C" void kernel_launch(void* const* d_in, const int* in_sizes, int n_in,
                              void* d_out, int out_size, void* d_ws, size_t ws_size,
                              hipStream_t stream) {
    const float* x  = (const float*)d_in[0];
    const float* w0 = (const float*)d_in[1];
    const float* b0 = (const float*)d_in[2];
    const float* w2 = (const float*)d_in[3];
    const float* b2 = (const float*)d_in[4];
    const float* w4 = (const float*)d_in[5];
    const float* b4 = (const float*)d_in[6];
    const float* w6 = (const float*)d_in[7];
    const float* b6 = (const float*)d_in[8];
    float* ws = (float*)d_ws;

    const int B  = in_sizes[0] / 16;
    const int n4 = B * 4;        // float4 elements of x
    const int nTiles = B / 64;   // full 64-row tiles

    // zero root + leaf counters (stream-ordered; capture-legal, proven R6/R8)
    hipMemsetAsync(ws, 0, (1 + NLEAF) * sizeof(unsigned), stream);
    k1_all<<<SCAN_BLOCKS + 1, 256, 0, stream>>>(
        (const float4*)x, w0, b0, w2, b2, w4, b4, w6, b6, ws, n4);
    k2_main<<<2048, 256, 0, stream>>>((const float4*)x, ws, (float4*)d_out, nTiles);
    const int tailStart = nTiles * 64;
    if (tailStart < B) {
        const int nTail = B - tailStart;
        k_tail<<<(nTail + 255) / 256, 256, 0, stream>>>(
            x, ws, (float*)d_out, tailStart, B);
    }
}

// Round 11
// 39.552 us; speedup vs baseline: 3.4429x; 3.4429x over previous
//
#include <hip/hip_runtime.h>

#define NLEV 127.0f
#define QEPS 1e-8f
#define SCAN_BLOCKS 2048

// ws float layout (NO counters — per-block cross-workgroup sync costs
// 40-130us on MI355X (R8/R10 lessons); kernel boundaries only):
// [0..2047]     per-scan-block |x| partial maxima (all written every call)
// [2304..2383]  T_lin[5][16]  (s-independent composite linear map)
// [2432..2564]  bpre[133] = b/w_sf, [l0:64 | l1:32 | l2:32 | l3:5]
// [2576..3240]  C[5][133] row-major bias-coefficient matrix (incl. L3 diag)
#define WS_PART 0
#define WS_TLIN 2304
#define WS_BPRE 2432
#define WS_C    2576

__device__ __forceinline__ float max4(float4 v) {
    return fmaxf(fmaxf(fabsf(v.x), fabsf(v.y)), fmaxf(fabsf(v.z), fabsf(v.w)));
}
__device__ __forceinline__ float clipr(float v) {
    return fminf(fmaxf(rintf(v), -NLEV), NLEV);
}

// ---- k1: block 0 composes all s-independent weight math (dispatched FIRST so
//      it fully overlaps the scan); blocks 1..SCAN_BLOCKS scan |x| -> partials.
//      No atomics, no fences — coherence comes from the kernel boundary. ----
__global__ void __launch_bounds__(256) k1_scan_compose(
        const float4* __restrict__ x4,
        const float* __restrict__ w0, const float* __restrict__ b0,
        const float* __restrict__ w2, const float* __restrict__ b2,
        const float* __restrict__ w4, const float* __restrict__ b4,
        const float* __restrict__ w6, const float* __restrict__ b6,
        float* __restrict__ ws, int n4) {
    const int t = threadIdx.x;

    if (blockIdx.x != 0) {
        // ---- scan chunk (blockIdx.x - 1) ----
        const int cid = blockIdx.x - 1;
        const int tid = cid * 256 + t;
        const int stride = SCAN_BLOCKS * 256;
        float m[8];
        #pragma unroll
        for (int k = 0; k < 8; ++k) m[k] = 0.f;
        int i = tid;
        for (; i + 7 * stride < n4; i += 8 * stride) {
            #pragma unroll
            for (int k = 0; k < 8; ++k) m[k] = fmaxf(m[k], max4(x4[i + k * stride]));
        }
        for (; i < n4; i += stride) m[0] = fmaxf(m[0], max4(x4[i]));
        float mm = fmaxf(fmaxf(fmaxf(m[0], m[1]), fmaxf(m[2], m[3])),
                         fmaxf(fmaxf(m[4], m[5]), fmaxf(m[6], m[7])));
        #pragma unroll
        for (int off = 32; off > 0; off >>= 1)
            mm = fmaxf(mm, __shfl_down(mm, off, 64));
        __shared__ float sm[4];
        if ((t & 63) == 0) sm[t >> 6] = mm;
        __syncthreads();
        if (t == 0)
            ws[WS_PART + cid] = fmaxf(fmaxf(sm[0], sm[1]), fmaxf(sm[2], sm[3]));
        return;
    }

    // ---- compose block (entirely s-independent), layers processed 3 -> 0 ----
    __shared__ float Wq[2048];          // max O*F = 32*64
    __shared__ float Rm[320], Rn[320], Cm[320];
    __shared__ float sfv[64];
    __shared__ unsigned rmax[64];

    const float* Wl[4] = {w0, w2, w4, w6};
    const float* Bl[4] = {b0, b2, b4, b6};
    const int Ol[4] = {64, 32, 32, 5};
    const int Fl[4] = {16, 64, 32, 32};
    const int bpre_off[4] = {0, 64, 96, 128};
    const int cs_base[4]  = {0, 64, 96, 128};

    for (int L = 3; L >= 0; --L) {
        const int O = Ol[L], F = Fl[L];
        const float* W = Wl[L];
        const float* Bb = Bl[L];
        if (t < 64) rmax[t] = 0u;
        __syncthreads();
        const int nf4 = O * F / 4, f4row = F / 4;
        for (int i = t; i < nf4; i += 256) {
            float4 wv = ((const float4*)W)[i];
            atomicMax(&rmax[i / f4row], __float_as_uint(max4(wv)));  // LDS atomic: fine
        }
        __syncthreads();
        if (t < O) {
            float sf = fmaxf(__uint_as_float(rmax[t]) / NLEV, QEPS);
            sfv[t] = sf;
            ws[WS_BPRE + bpre_off[L] + t] = Bb[t] / sf;
        }
        __syncthreads();
        for (int i = t; i < O * F; i += 256)
            Wq[i] = clipr(W[i] / sfv[i / F]);
        __syncthreads();

        if (L == 3) {
            for (int i = t; i < 5 * F; i += 256) Rm[i] = sfv[i / F] * Wq[i];
            if (t < 25) {
                int oo = t / 5, k = t % 5;
                ws[WS_C + oo * 133 + cs_base[3] + k] = (k == oo) ? sfv[oo] : 0.f;
            }
            __syncthreads();
        } else {
            for (int i = t; i < 5 * O; i += 256) {
                int r = i / O, c0 = i % O;
                float v = Rm[r * O + c0] * sfv[c0];
                Cm[i] = v;
                ws[WS_C + r * 133 + cs_base[L] + c0] = v;
            }
            __syncthreads();
            for (int i = t; i < 5 * F; i += 256) {
                int r = i / F, c0 = i % F;
                float acc = 0.f;
                #pragma unroll 8
                for (int j = 0; j < O; ++j) acc += Cm[r * O + j] * Wq[j * F + c0];
                Rn[i] = acc;
            }
            __syncthreads();
            if (L == 0) {
                for (int i = t; i < 80; i += 256) ws[WS_TLIN + i] = Rn[i];
            } else {
                for (int i = t; i < 5 * F; i += 256) Rm[i] = Rn[i];
                __syncthreads();
            }
        }
    }
}

// Shared self-finalize prologue: partials -> s; bi; c = s*C.bi; Msh = s*T_lin.
// Thin on purpose (R7 lesson: fat prologues inflate the whole kernel's VGPRs).
__device__ __forceinline__ void finalize_prologue(const float* __restrict__ ws,
                                                  float* bi, float* Msh, float* csh,
                                                  float* red, float* s_out) {
    const int t = threadIdx.x;
    float pm = 0.f;
    for (int i = t; i < SCAN_BLOCKS; i += 256) pm = fmaxf(pm, ws[WS_PART + i]);
    #pragma unroll
    for (int off = 32; off > 0; off >>= 1)
        pm = fmaxf(pm, __shfl_down(pm, off, 64));
    if ((t & 63) == 0) red[t >> 6] = pm;
    __syncthreads();
    if (t == 0) {
        float am = fmaxf(fmaxf(red[0], red[1]), fmaxf(red[2], red[3]));
        *s_out = fmaxf(am / NLEV, QEPS);
    }
    __syncthreads();
    const float s = *s_out;
    const float inv_s = 1.0f / s;

    if (t < 133) bi[t] = clipr(ws[WS_BPRE + t] * inv_s);
    __syncthreads();
    if (t < 160) {
        // c[oo] = s * dot(C[oo][:], bi) — 32-lane groups ALIGNED to lane
        // boundaries (R8 bug: +80 offset made shfl groups straddle inactive lanes)
        const int oo = t >> 5, lane = t & 31;
        float acc = 0.f;
        for (int j = lane; j < 133; j += 32)
            acc += ws[WS_C + oo * 133 + j] * bi[j];
        #pragma unroll
        for (int off = 16; off > 0; off >>= 1)
            acc += __shfl_xor(acc, off, 32);
        if (lane == 0) csh[oo] = acc * s;
    } else if (t < 240) {
        Msh[t - 160] = ws[WS_TLIN + (t - 160)] * s;
    }
    __syncthreads();
}

// ---- k2: self-finalizing prologue + streaming main pass ----
__global__ void __launch_bounds__(256, 6) k2_main(const float4* __restrict__ x4,
                                                  const float* __restrict__ ws,
                                                  float4* __restrict__ out4,
                                                  int nTiles) {
    __shared__ __align__(16) float ostage[640];
    __shared__ float bi[133], Msh[80], csh[5], red[4], s_sh;
    const int t = threadIdx.x;
    const int v = t & 3;
    const int lrow = t >> 2;

    finalize_prologue(ws, bi, Msh, csh, red, &s_sh);
    const float inv_s = 1.0f / s_sh;

    float Mreg[5][4], cadd[5];
    #pragma unroll
    for (int oo = 0; oo < 5; ++oo) {
        cadd[oo] = csh[oo];
        #pragma unroll
        for (int j = 0; j < 4; ++j) Mreg[oo][j] = Msh[oo * 16 + v * 4 + j];
    }

    int parity = 0;
    int tile = blockIdx.x;
    float4 xv = make_float4(0.f, 0.f, 0.f, 0.f);
    if (tile < nTiles) xv = x4[(size_t)tile * 256 + t];
    for (; tile < nTiles; tile += gridDim.x, parity ^= 1) {
        const int nt = tile + gridDim.x;
        float4 xn = make_float4(0.f, 0.f, 0.f, 0.f);
        if (nt < nTiles) xn = x4[(size_t)nt * 256 + t];

        float q0 = fminf(fmaxf(rintf(xv.x * inv_s), -NLEV), NLEV);
        float q1 = fminf(fmaxf(rintf(xv.y * inv_s), -NLEV), NLEV);
        float q2 = fminf(fmaxf(rintf(xv.z * inv_s), -NLEV), NLEV);
        float q3 = fminf(fmaxf(rintf(xv.w * inv_s), -NLEV), NLEV);

        float* buf = ostage + (parity ? 320 : 0);
        float p[5];
        #pragma unroll
        for (int oo = 0; oo < 5; ++oo) {
            float acc = fmaf(q0, Mreg[oo][0],
                        fmaf(q1, Mreg[oo][1],
                        fmaf(q2, Mreg[oo][2], q3 * Mreg[oo][3])));
            acc += __shfl_xor(acc, 1, 64);
            acc += __shfl_xor(acc, 2, 64);
            p[oo] = acc;
        }
        if (v == 0) {
            #pragma unroll
            for (int oo = 0; oo < 5; ++oo) buf[lrow * 5 + oo] = p[oo] + cadd[oo];
        }
        __syncthreads();
        if (t < 80) out4[(size_t)tile * 80 + t] = ((const float4*)buf)[t];
        xv = xn;
    }
}

// ---- tail rows (only launched when B % 64 != 0; never for B=1M) ----
__global__ void __launch_bounds__(256) k_tail(const float* __restrict__ x,
                                              const float* __restrict__ ws,
                                              float* __restrict__ out,
                                              int tailStart, int B) {
    __shared__ float bi[133], Msh[80], csh[5], red[4], s_sh;
    finalize_prologue(ws, bi, Msh, csh, red, &s_sh);
    const float inv_s = 1.0f / s_sh;
    const int r = tailStart + blockIdx.x * 256 + threadIdx.x;
    if (r >= B) return;
    const float* xr = x + (size_t)r * 16;
    float q[16];
    #pragma unroll
    for (int i = 0; i < 16; ++i)
        q[i] = fminf(fmaxf(rintf(xr[i] * inv_s), -NLEV), NLEV);
    #pragma unroll
    for (int oo = 0; oo < 5; ++oo) {
        float acc = csh[oo];
        #pragma unroll
        for (int i = 0; i < 16; ++i) acc = fmaf(q[i], Msh[oo * 16 + i], acc);
        out[(size_t)r * 5 + oo] = acc;
    }
}

extern "C" void kernel_launch(void* const* d_in, const int* in_sizes, int n_in,
                              void* d_out, int out_size, void* d_ws, size_t ws_size,
                              hipStream_t stream) {
    const float* x  = (const float*)d_in[0];
    const float* w0 = (const float*)d_in[1];
    const float* b0 = (const float*)d_in[2];
    const float* w2 = (const float*)d_in[3];
    const float* b2 = (const float*)d_in[4];
    const float* w4 = (const float*)d_in[5];
    const float* b4 = (const float*)d_in[6];
    const float* w6 = (const float*)d_in[7];
    const float* b6 = (const float*)d_in[8];
    float* ws = (float*)d_ws;

    const int B  = in_sizes[0] / 16;
    const int n4 = B * 4;        // float4 elements of x
    const int nTiles = B / 64;   // full 64-row tiles

    k1_scan_compose<<<SCAN_BLOCKS + 1, 256, 0, stream>>>(
        (const float4*)x, w0, b0, w2, b2, w4, b4, w6, b6, ws, n4);
    k2_main<<<2048, 256, 0, stream>>>((const float4*)x, ws, (float4*)d_out, nTiles);
    const int tailStart = nTiles * 64;
    if (tailStart < B) {
        const int nTail = B - tailStart;
        k_tail<<<(nTail + 255) / 256, 256, 0, stream>>>(
            x, ws, (float*)d_out, tailStart, B);
    }
}

// Round 12
// 36.824 us; speedup vs baseline: 3.6980x; 1.0741x over previous
//
#include <hip/hip_runtime.h>

#define NLEV 127.0f
#define QEPS 1e-8f
#define SCAN_BLOCKS 1024

// ws float layout (NO counters, NO cross-workgroup sync — per-block scoped
// fences/atomics cost 40-130us on MI355X (R8/R10); kernel boundaries only):
// [0..1023]     per-scan-block |x| partial maxima (all written every call)
// [2304..2383]  T_lin[5][16]  (s-independent composite linear map)
// [2432..2564]  bpre[133] = b/w_sf, [l0:64 | l1:32 | l2:32 | l3:5]
// [2576..3240]  C[5][133] row-major bias-coefficient matrix (incl. L3 diag)
#define WS_PART 0
#define WS_TLIN 2304
#define WS_BPRE 2432
#define WS_C    2576

__device__ __forceinline__ float max4(float4 v) {
    return fmaxf(fmaxf(fabsf(v.x), fabsf(v.y)), fmaxf(fabsf(v.z), fabsf(v.w)));
}
__device__ __forceinline__ float clipr(float v) {
    return fminf(fmaxf(rintf(v), -NLEV), NLEV);
}

// ---- k1: block 0 composes all s-independent weight math (dispatched FIRST so
//      it overlaps the scan); blocks 1..SCAN_BLOCKS scan |x| -> partials.
//      Scan is tile-linear (contiguous 1KB/wave requests, 16 float4/thread in
//      two 8-deep ILP rounds) — k2's measured-good pattern, more work/block. ----
__global__ void __launch_bounds__(256) k1_scan_compose(
        const float4* __restrict__ x4,
        const float* __restrict__ w0, const float* __restrict__ b0,
        const float* __restrict__ w2, const float* __restrict__ b2,
        const float* __restrict__ w4, const float* __restrict__ b4,
        const float* __restrict__ w6, const float* __restrict__ b6,
        float* __restrict__ ws, int n4) {
    const int t = threadIdx.x;

    if (blockIdx.x != 0) {
        const int cid = blockIdx.x - 1;
        // per-block contiguous range: ceil(n4 / SCAN_BLOCKS), rounded to 2048
        const int perBlk = ((n4 + SCAN_BLOCKS - 1) / SCAN_BLOCKS + 2047) & ~2047;
        const int base = cid * perBlk;
        float m[8];
        #pragma unroll
        for (int k = 0; k < 8; ++k) m[k] = 0.f;
        for (int r = 0; r < perBlk; r += 2048) {
            const int rb = base + r + t;
            #pragma unroll
            for (int k = 0; k < 8; ++k) {
                const int idx = rb + k * 256;
                if (idx < n4) m[k] = fmaxf(m[k], max4(x4[idx]));
            }
        }
        float mm = fmaxf(fmaxf(fmaxf(m[0], m[1]), fmaxf(m[2], m[3])),
                         fmaxf(fmaxf(m[4], m[5]), fmaxf(m[6], m[7])));
        #pragma unroll
        for (int off = 32; off > 0; off >>= 1)
            mm = fmaxf(mm, __shfl_down(mm, off, 64));
        __shared__ float sm[4];
        if ((t & 63) == 0) sm[t >> 6] = mm;
        __syncthreads();
        if (t == 0)
            ws[WS_PART + cid] = fmaxf(fmaxf(sm[0], sm[1]), fmaxf(sm[2], sm[3]));
        return;
    }

    // ---- compose block (entirely s-independent), layers processed 3 -> 0 ----
    __shared__ float Wq[2048];          // max O*F = 32*64
    __shared__ float Rm[320], Rn[320], Cm[320];
    __shared__ float sfv[64];
    __shared__ unsigned rmax[64];

    const float* Wl[4] = {w0, w2, w4, w6};
    const float* Bl[4] = {b0, b2, b4, b6};
    const int Ol[4] = {64, 32, 32, 5};
    const int Fl[4] = {16, 64, 32, 32};
    const int bpre_off[4] = {0, 64, 96, 128};
    const int cs_base[4]  = {0, 64, 96, 128};

    for (int L = 3; L >= 0; --L) {
        const int O = Ol[L], F = Fl[L];
        const float* W = Wl[L];
        const float* Bb = Bl[L];
        if (t < 64) rmax[t] = 0u;
        __syncthreads();
        const int nf4 = O * F / 4, f4row = F / 4;
        for (int i = t; i < nf4; i += 256) {
            float4 wv = ((const float4*)W)[i];
            atomicMax(&rmax[i / f4row], __float_as_uint(max4(wv)));  // LDS atomic: fine
        }
        __syncthreads();
        if (t < O) {
            float sf = fmaxf(__uint_as_float(rmax[t]) / NLEV, QEPS);
            sfv[t] = sf;
            ws[WS_BPRE + bpre_off[L] + t] = Bb[t] / sf;
        }
        __syncthreads();
        for (int i = t; i < O * F; i += 256)
            Wq[i] = clipr(W[i] / sfv[i / F]);
        __syncthreads();

        if (L == 3) {
            for (int i = t; i < 5 * F; i += 256) Rm[i] = sfv[i / F] * Wq[i];
            if (t < 25) {
                int oo = t / 5, k = t % 5;
                ws[WS_C + oo * 133 + cs_base[3] + k] = (k == oo) ? sfv[oo] : 0.f;
            }
            __syncthreads();
        } else {
            for (int i = t; i < 5 * O; i += 256) {
                int r = i / O, c0 = i % O;
                float v = Rm[r * O + c0] * sfv[c0];
                Cm[i] = v;
                ws[WS_C + r * 133 + cs_base[L] + c0] = v;
            }
            __syncthreads();
            for (int i = t; i < 5 * F; i += 256) {
                int r = i / F, c0 = i % F;
                float acc = 0.f;
                #pragma unroll 8
                for (int j = 0; j < O; ++j) acc += Cm[r * O + j] * Wq[j * F + c0];
                Rn[i] = acc;
            }
            __syncthreads();
            if (L == 0) {
                for (int i = t; i < 80; i += 256) ws[WS_TLIN + i] = Rn[i];
            } else {
                for (int i = t; i < 5 * F; i += 256) Rm[i] = Rn[i];
                __syncthreads();
            }
        }
    }
}

// Shared self-finalize prologue: partials -> s; bi; c = s*C.bi; Msh = s*T_lin.
// Thin on purpose (R7 lesson: fat prologues inflate the whole kernel's VGPRs).
__device__ __forceinline__ void finalize_prologue(const float* __restrict__ ws,
                                                  float* bi, float* Msh, float* csh,
                                                  float* red, float* s_out) {
    const int t = threadIdx.x;
    float pm = 0.f;
    for (int i = t; i < SCAN_BLOCKS; i += 256) pm = fmaxf(pm, ws[WS_PART + i]);
    #pragma unroll
    for (int off = 32; off > 0; off >>= 1)
        pm = fmaxf(pm, __shfl_down(pm, off, 64));
    if ((t & 63) == 0) red[t >> 6] = pm;
    __syncthreads();
    if (t == 0) {
        float am = fmaxf(fmaxf(red[0], red[1]), fmaxf(red[2], red[3]));
        *s_out = fmaxf(am / NLEV, QEPS);
    }
    __syncthreads();
    const float s = *s_out;
    const float inv_s = 1.0f / s;

    if (t < 133) bi[t] = clipr(ws[WS_BPRE + t] * inv_s);
    __syncthreads();
    if (t < 160) {
        // c[oo] = s * dot(C[oo][:], bi) — 32-lane groups ALIGNED to lane
        // boundaries (R8 bug: +80 offset made shfl groups straddle inactive lanes)
        const int oo = t >> 5, lane = t & 31;
        float acc = 0.f;
        for (int j = lane; j < 133; j += 32)
            acc += ws[WS_C + oo * 133 + j] * bi[j];
        #pragma unroll
        for (int off = 16; off > 0; off >>= 1)
            acc += __shfl_xor(acc, off, 32);
        if (lane == 0) csh[oo] = acc * s;
    } else if (t < 240) {
        Msh[t - 160] = ws[WS_TLIN + (t - 160)] * s;
    }
    __syncthreads();
}

// ---- k2: self-finalizing prologue + streaming main pass (R11, unchanged) ----
__global__ void __launch_bounds__(256, 6) k2_main(const float4* __restrict__ x4,
                                                  const float* __restrict__ ws,
                                                  float4* __restrict__ out4,
                                                  int nTiles) {
    __shared__ __align__(16) float ostage[640];
    __shared__ float bi[133], Msh[80], csh[5], red[4], s_sh;
    const int t = threadIdx.x;
    const int v = t & 3;
    const int lrow = t >> 2;

    finalize_prologue(ws, bi, Msh, csh, red, &s_sh);
    const float inv_s = 1.0f / s_sh;

    float Mreg[5][4], cadd[5];
    #pragma unroll
    for (int oo = 0; oo < 5; ++oo) {
        cadd[oo] = csh[oo];
        #pragma unroll
        for (int j = 0; j < 4; ++j) Mreg[oo][j] = Msh[oo * 16 + v * 4 + j];
    }

    int parity = 0;
    int tile = blockIdx.x;
    float4 xv = make_float4(0.f, 0.f, 0.f, 0.f);
    if (tile < nTiles) xv = x4[(size_t)tile * 256 + t];
    for (; tile < nTiles; tile += gridDim.x, parity ^= 1) {
        const int nt = tile + gridDim.x;
        float4 xn = make_float4(0.f, 0.f, 0.f, 0.f);
        if (nt < nTiles) xn = x4[(size_t)nt * 256 + t];

        float q0 = fminf(fmaxf(rintf(xv.x * inv_s), -NLEV), NLEV);
        float q1 = fminf(fmaxf(rintf(xv.y * inv_s), -NLEV), NLEV);
        float q2 = fminf(fmaxf(rintf(xv.z * inv_s), -NLEV), NLEV);
        float q3 = fminf(fmaxf(rintf(xv.w * inv_s), -NLEV), NLEV);

        float* buf = ostage + (parity ? 320 : 0);
        float p[5];
        #pragma unroll
        for (int oo = 0; oo < 5; ++oo) {
            float acc = fmaf(q0, Mreg[oo][0],
                        fmaf(q1, Mreg[oo][1],
                        fmaf(q2, Mreg[oo][2], q3 * Mreg[oo][3])));
            acc += __shfl_xor(acc, 1, 64);
            acc += __shfl_xor(acc, 2, 64);
            p[oo] = acc;
        }
        if (v == 0) {
            #pragma unroll
            for (int oo = 0; oo < 5; ++oo) buf[lrow * 5 + oo] = p[oo] + cadd[oo];
        }
        __syncthreads();
        if (t < 80) out4[(size_t)tile * 80 + t] = ((const float4*)buf)[t];
        xv = xn;
    }
}

// ---- tail rows (only launched when B % 64 != 0; never for B=1M) ----
__global__ void __launch_bounds__(256) k_tail(const float* __restrict__ x,
                                              const float* __restrict__ ws,
                                              float* __restrict__ out,
                                              int tailStart, int B) {
    __shared__ float bi[133], Msh[80], csh[5], red[4], s_sh;
    finalize_prologue(ws, bi, Msh, csh, red, &s_sh);
    const float inv_s = 1.0f / s_sh;
    const int r = tailStart + blockIdx.x * 256 + threadIdx.x;
    if (r >= B) return;
    const float* xr = x + (size_t)r * 16;
    float q[16];
    #pragma unroll
    for (int i = 0; i < 16; ++i)
        q[i] = fminf(fmaxf(rintf(xr[i] * inv_s), -NLEV), NLEV);
    #pragma unroll
    for (int oo = 0; oo < 5; ++oo) {
        float acc = csh[oo];
        #pragma unroll
        for (int i = 0; i < 16; ++i) acc = fmaf(q[i], Msh[oo * 16 + i], acc);
        out[(size_t)r * 5 + oo] = acc;
    }
}

extern "C" void kernel_launch(void* const* d_in, const int* in_sizes, int n_in,
                              void* d_out, int out_size, void* d_ws, size_t ws_size,
                              hipStream_t stream) {
    const float* x  = (const float*)d_in[0];
    const float* w0 = (const float*)d_in[1];
    const float* b0 = (const float*)d_in[2];
    const float* w2 = (const float*)d_in[3];
    const float* b2 = (const float*)d_in[4];
    const float* w4 = (const float*)d_in[5];
    const float* b4 = (const float*)d_in[6];
    const float* w6 = (const float*)d_in[7];
    const float* b6 = (const float*)d_in[8];
    float* ws = (float*)d_ws;

    const int B  = in_sizes[0] / 16;
    const int n4 = B * 4;        // float4 elements of x
    const int nTiles = B / 64;   // full 64-row tiles

    k1_scan_compose<<<SCAN_BLOCKS + 1, 256, 0, stream>>>(
        (const float4*)x, w0, b0, w2, b2, w4, b4, w6, b6, ws, n4);
    k2_main<<<2048, 256, 0, stream>>>((const float4*)x, ws, (float4*)d_out, nTiles);
    const int tailStart = nTiles * 64;
    if (tailStart < B) {
        const int nTail = B - tailStart;
        k_tail<<<(nTail + 255) / 256, 256, 0, stream>>>(
            x, ws, (float*)d_out, tailStart, B);
    }
}